// Round 2
// baseline (1112.948 us; speedup 1.0000x reference)
//
#include <hip/hip_runtime.h>
#include <hip/hip_bf16.h>
#include <math.h>

// Bloom attention block. Inputs/outputs fp32; bf16 MFMA internally.
// B=1, S=2048, HID=4096, NH=32, HD=128.
// Pipeline: QKV GEMM -> flash attention (causal + alibi) -> dense GEMM.

typedef __attribute__((ext_vector_type(8))) short short8;
typedef __attribute__((ext_vector_type(4))) float floatx4;

#define S_LEN 2048
#define HID_DIM 4096
#define NHEADS 32
#define HDIM 128
#define QKV_N 12288
#define INV_NORM 0.08838834764831845f  // 1/sqrt(128)

__device__ __forceinline__ float bf2f(unsigned short u) {
    union { unsigned int i; float f; } v; v.i = ((unsigned int)u) << 16; return v.f;
}
// RNE rounding (used only at epilogue stores)
__device__ __forceinline__ unsigned short f2bf(float f) {
    union { float f; unsigned int i; } v; v.f = f;
    unsigned int u = v.i;
    return (unsigned short)((u + 0x7fffu + ((u >> 16) & 1u)) >> 16);
}
// pack two fp32 -> two bf16 (truncation) in ONE v_perm_b32
__device__ __forceinline__ unsigned pack2_bf16(float f0, float f1) {
    union { float f; unsigned u; } a, b; a.f = f1; b.f = f0;
    // src0 (a=f1) supplies result bytes 2,3 (sel 6,7); src1 (b=f0) bytes 0,1 (sel 2,3)
    return __builtin_amdgcn_perm(a.u, b.u, 0x07060302u);
}

// load 8 contiguous elements as bf16 short8
__device__ __forceinline__ short8 ld8(const unsigned short* p) { return *(const short8*)p; }
__device__ __forceinline__ short8 ld8(const float* p) {
    const float4* q = (const float4*)p;
    float4 x = q[0], y = q[1];
    union { unsigned u[4]; short8 s; } r;
    r.u[0] = pack2_bf16(x.x, x.y);
    r.u[1] = pack2_bf16(x.z, x.w);
    r.u[2] = pack2_bf16(y.x, y.y);
    r.u[3] = pack2_bf16(y.z, y.w);
    return r.s;
}
__device__ __forceinline__ void st1(unsigned short* p, float v) { *p = f2bf(v); }
__device__ __forceinline__ void st1(float* p, float v) { *p = v; }

// ---------------------------------------------------------------------------
// GEMM: C[m][n] = sum_k A[m][k] * B[n][k] + bias[n]   (A: MxK, B: NxK)
// 128x128 tile, BK=64, 4 waves (2x2 of 64x64), 16x16x32 bf16 MFMA.
// LDS rows padded to 72 elements (144 B -> 4-bank rotation, conflict-free).
// ---------------------------------------------------------------------------
#define LDT 72

template <typename TA, typename TB, typename TC>
__global__ __launch_bounds__(256) void gemm_bt_bias(
    const TA* __restrict__ A,
    const TB* __restrict__ B,
    const float* __restrict__ bias,
    TC* __restrict__ C,
    int M, int N, int K)
{
    __shared__ unsigned short a_lds[128 * LDT];
    __shared__ unsigned short b_lds[128 * LDT];
    int t = threadIdx.x;
    int w = t >> 6, lane = t & 63, quad = lane >> 4, l15 = lane & 15;
    int mb = blockIdx.y * 128, nb = blockIdx.x * 128;
    int wm = (w >> 1) * 64, wn = (w & 1) * 64;

    floatx4 acc[4][4];
    for (int i = 0; i < 4; i++)
        for (int j = 0; j < 4; j++) acc[i][j] = (floatx4)0.0f;

    for (int k0 = 0; k0 < K; k0 += 64) {
        for (int i = 0; i < 4; i++) {
            int idx = t + 256 * i;
            int row = idx >> 3;          // 8 chunks of 8 elems per row
            int col = (idx & 7) * 8;
            *(short8*)&a_lds[row * LDT + col] = ld8(&A[(size_t)(mb + row) * K + k0 + col]);
            *(short8*)&b_lds[row * LDT + col] = ld8(&B[(size_t)(nb + row) * K + k0 + col]);
        }
        __syncthreads();
        for (int ks = 0; ks < 2; ks++) {
            short8 af[4], bfr[4];
            for (int i = 0; i < 4; i++)
                af[i] = *(const short8*)&a_lds[(wm + i * 16 + l15) * LDT + ks * 32 + quad * 8];
            for (int j = 0; j < 4; j++)
                bfr[j] = *(const short8*)&b_lds[(wn + j * 16 + l15) * LDT + ks * 32 + quad * 8];
            for (int i = 0; i < 4; i++)
                for (int j = 0; j < 4; j++)
                    acc[i][j] = __builtin_amdgcn_mfma_f32_16x16x32_bf16(af[i], bfr[j], acc[i][j], 0, 0, 0);
        }
        __syncthreads();
    }

    for (int j = 0; j < 4; j++) {
        int col = nb + wn + j * 16 + l15;
        float bv = bias[col];
        for (int i = 0; i < 4; i++) {
            int rowbase = mb + wm + i * 16 + quad * 4;
            for (int r = 0; r < 4; r++)
                st1(&C[(size_t)(rowbase + r) * N + col], acc[i][j][r] + bv);
        }
    }
}

// ---------------------------------------------------------------------------
// Flash attention, causal + alibi. One block per (head, 64-row q tile).
// 4 waves x 16 q-rows. K-tiles of 64 keys. fused layout: [S][NH*3*HD] bf16,
// per head h: Q at h*384, K at h*384+128, V at h*384+256.
// ---------------------------------------------------------------------------
__global__ __launch_bounds__(256) void attn_flash(
    const unsigned short* __restrict__ fused,   // [S][12288] bf16
    const float* __restrict__ alibi,            // [NH][S] fp32
    unsigned short* __restrict__ ctx)           // [S][4096] bf16
{
    __shared__ unsigned short k_lds[64 * 136];   // [key][d], pad 128->136
    __shared__ unsigned short vt_lds[128 * 72];  // [d][key], pad 64->72
    __shared__ unsigned short p_lds[4 * 16 * 72];

    int h = blockIdx.x;
    int qb = blockIdx.y * 64;
    int t = threadIdx.x;
    int w = t >> 6, lane = t & 63, quad = lane >> 4, l15 = lane & 15;
    const size_t rowstr = QKV_N;
    int qoff = h * 384;

    // Q fragments (A-layout) for this wave's 16 q rows, all 128 dims
    short8 qf[4];
    {
        int qrow = qb + w * 16 + l15;
        const unsigned short* qp = fused + (size_t)qrow * rowstr + qoff;
        for (int ks = 0; ks < 4; ks++)
            qf[ks] = *(const short8*)&qp[ks * 32 + quad * 8];
    }

    floatx4 o[8];
    for (int j = 0; j < 8; j++) o[j] = (floatx4)0.0f;
    float m_prev[4], l_prev[4];
    for (int r = 0; r < 4; r++) { m_prev[r] = -INFINITY; l_prev[r] = 0.0f; }

    int ntiles = qb / 64 + 1;
    for (int tile = 0; tile < ntiles; tile++) {
        int kb = tile * 64;
        // stage K tile [64][128] and V^T [128][64]
        for (int i = 0; i < 4; i++) {
            int idx = t + 256 * i;
            int row = idx >> 4;            // 16 chunks of 8 per 128-wide row
            int col = (idx & 15) * 8;
            const unsigned short* kp = fused + (size_t)(kb + row) * rowstr + qoff + 128 + col;
            *(short8*)&k_lds[row * 136 + col] = *(const short8*)kp;
            short8 vv = *(const short8*)(fused + (size_t)(kb + row) * rowstr + qoff + 256 + col);
            for (int jj = 0; jj < 8; jj++)
                vt_lds[(col + jj) * 72 + row] = (unsigned short)vv[jj];
        }
        __syncthreads();

        // S = Q K^T (per wave: 16 q-rows x 64 keys)
        floatx4 s[4];
        for (int j = 0; j < 4; j++) s[j] = (floatx4)0.0f;
        for (int ks = 0; ks < 4; ks++) {
            for (int j = 0; j < 4; j++) {
                short8 bfr = *(const short8*)&k_lds[(j * 16 + l15) * 136 + ks * 32 + quad * 8];
                s[j] = __builtin_amdgcn_mfma_f32_16x16x32_bf16(qf[ks], bfr, s[j], 0, 0, 0);
            }
        }

        // scale + alibi + causal mask
        float sv[4][4];
        for (int j = 0; j < 4; j++) {
            int kcol = kb + j * 16 + l15;
            float al = alibi[h * S_LEN + kcol];
            for (int r = 0; r < 4; r++) {
                int qrow = qb + w * 16 + quad * 4 + r;
                float x = s[j][r] * INV_NORM + al;
                sv[j][r] = (kcol <= qrow) ? x : -INFINITY;
            }
        }

        // online softmax per q-row (rows live in one contiguous 16-lane group)
        float p[4][4];
        for (int r = 0; r < 4; r++) {
            float mt = fmaxf(fmaxf(sv[0][r], sv[1][r]), fmaxf(sv[2][r], sv[3][r]));
            for (int off = 1; off < 16; off <<= 1)
                mt = fmaxf(mt, __shfl_xor(mt, off, 64));
            float m_new = fmaxf(m_prev[r], mt);
            float alpha = expf(m_prev[r] - m_new);     // exp(-inf)=0 first tile
            float rs = 0.0f;
            for (int j = 0; j < 4; j++) {
                float pv = expf(sv[j][r] - m_new);     // masked -> exp(-inf)=0
                p[j][r] = pv;
                rs += pv;
            }
            for (int off = 1; off < 16; off <<= 1)
                rs += __shfl_xor(rs, off, 64);
            l_prev[r] = l_prev[r] * alpha + rs;
            m_prev[r] = m_new;
            for (int j = 0; j < 8; j++) o[j][r] *= alpha;
        }

        // P (C-layout) -> LDS -> A-layout fragments (per-wave region, no barrier)
        {
            unsigned short* pb = &p_lds[w * 16 * 72];
            for (int j = 0; j < 4; j++)
                for (int r = 0; r < 4; r++)
                    pb[(quad * 4 + r) * 72 + j * 16 + l15] = f2bf(p[j][r]);
        }
        {
            const unsigned short* pb = &p_lds[w * 16 * 72];
            for (int ks = 0; ks < 2; ks++) {
                short8 ap = *(const short8*)&pb[l15 * 72 + ks * 32 + quad * 8];
                for (int j = 0; j < 8; j++) {
                    short8 bv = *(const short8*)&vt_lds[(j * 16 + l15) * 72 + ks * 32 + quad * 8];
                    o[j] = __builtin_amdgcn_mfma_f32_16x16x32_bf16(ap, bv, o[j], 0, 0, 0);
                }
            }
        }
        __syncthreads();
    }

    // normalize and store ctx in [S][HID] layout (head h at cols h*128..)
    for (int r = 0; r < 4; r++) {
        float linv = 1.0f / l_prev[r];
        int qrow = qb + w * 16 + quad * 4 + r;
        unsigned short* op = ctx + (size_t)qrow * HID_DIM + h * HDIM;
        for (int j = 0; j < 8; j++)
            op[j * 16 + l15] = f2bf(o[j][r] * linv);
    }
}

extern "C" void kernel_launch(void* const* d_in, const int* in_sizes, int n_in,
                              void* d_out, int out_size, void* d_ws, size_t ws_size,
                              hipStream_t stream) {
    const float* hidden  = (const float*)d_in[0];  // [1,2048,4096] fp32
    const float* alibi   = (const float*)d_in[1];  // [32,1,2048]   fp32
    const float* w_qkv   = (const float*)d_in[2];  // [12288,4096]  fp32
    const float* b_qkv   = (const float*)d_in[3];  // [12288]       fp32
    const float* w_dense = (const float*)d_in[4];  // [4096,4096]   fp32
    const float* b_dense = (const float*)d_in[5];  // [4096]        fp32
    float* out = (float*)d_out;                    // [2048,4096]   fp32

    unsigned short* fused = (unsigned short*)d_ws;             // [2048][12288] bf16
    unsigned short* ctx   = fused + (size_t)S_LEN * QKV_N;     // [2048][4096]  bf16

    dim3 blk(256);
    // QKV projection: fused = bf16(hidden @ w_qkv^T + b_qkv)
    gemm_bt_bias<<<dim3(QKV_N / 128, S_LEN / 128), blk, 0, stream>>>(
        hidden, w_qkv, b_qkv, fused, S_LEN, QKV_N, HID_DIM);
    // attention
    attn_flash<<<dim3(NHEADS, S_LEN / 64), blk, 0, stream>>>(fused, alibi, ctx);
    // output projection: out = ctx @ w_dense^T + b_dense (fp32 out)
    gemm_bt_bias<<<dim3(HID_DIM / 128, S_LEN / 128), blk, 0, stream>>>(
        ctx, w_dense, b_dense, out, S_LEN, HID_DIM, HID_DIM);
}

// Round 3
// 850.577 us; speedup vs baseline: 1.3085x; 1.3085x over previous
//
#include <hip/hip_runtime.h>
#include <math.h>

// Bloom attention block. Inputs/outputs fp32; bf16 MFMA internally.
// B=1, S=2048, HID=4096, NH=32, HD=128.
// Pipeline: fp32->bf16 convert -> QKV GEMM (writes Q/K compact + V transposed)
//           -> flash attention -> dense GEMM.

typedef __attribute__((ext_vector_type(8))) short short8;
typedef __attribute__((ext_vector_type(4))) float floatx4;
typedef __attribute__((ext_vector_type(4))) unsigned short ushort4v;

#define S_LEN 2048
#define HID_DIM 4096
#define NHEADS 32
#define HDIM 128
#define QKV_N 12288
#define QK_STRIDE 8192            // compact [S][NH*256] Q/K buffer
#define INV_NORM 0.08838834764831845f  // 1/sqrt(128)

__device__ __forceinline__ unsigned short f2bf(float f) {
    union { float f; unsigned int i; } v; v.f = f;
    unsigned int u = v.i;
    return (unsigned short)((u + 0x7fffu + ((u >> 16) & 1u)) >> 16);
}

// async 16B/lane global->LDS (lds dest = wave-uniform base + lane*16)
typedef __attribute__((address_space(1))) unsigned int guint;
typedef __attribute__((address_space(3))) unsigned int luint;
__device__ __forceinline__ void gl_lds16(const unsigned short* g, unsigned short* l) {
    __builtin_amdgcn_global_load_lds((guint*)g, (luint*)l, 16, 0, 0);
}

// ---------------------------------------------------------------------------
// fp32 -> bf16 (RNE), 8 elems/thread, exact grids
// ---------------------------------------------------------------------------
__global__ __launch_bounds__(256) void cvt_bf16(
    const float* __restrict__ src, unsigned short* __restrict__ dst)
{
    size_t i = ((size_t)blockIdx.x * 256 + threadIdx.x) * 8;
    float4 x = *(const float4*)(src + i);
    float4 y = *(const float4*)(src + i + 4);
    union { unsigned u[4]; short8 s; } r;
    r.u[0] = (unsigned)f2bf(x.x) | ((unsigned)f2bf(x.y) << 16);
    r.u[1] = (unsigned)f2bf(x.z) | ((unsigned)f2bf(x.w) << 16);
    r.u[2] = (unsigned)f2bf(y.x) | ((unsigned)f2bf(y.y) << 16);
    r.u[3] = (unsigned)f2bf(y.z) | ((unsigned)f2bf(y.w) << 16);
    *(short8*)(dst + i) = r.s;
}

// ---------------------------------------------------------------------------
// GEMM: C[m][n] = sum_k A[m][k]*B[n][k] + bias[n]  (bf16 in, 128x128 tile,
// BK=64, 4 waves 2x2 of 64x64). Staging via global_load_lds(16B) into
// unpadded LDS; XOR chunk swizzle applied on the GLOBAL address so fragment
// ds_read_b128 spreads over all 32 banks (2 lanes/bank = free).
// MODE 0: fp32 out [M][N].  MODE 1: QKV — Q/K to compact [S][8192] bf16,
// V written transposed to vt[h][d][s] (block-uniform: 384 = 3*128).
// ---------------------------------------------------------------------------
template <int MODE>
__global__ __launch_bounds__(256) void gemm_bt(
    const unsigned short* __restrict__ A,
    const unsigned short* __restrict__ B,
    const float* __restrict__ bias,
    unsigned short* __restrict__ Cq,
    float* __restrict__ Cf,
    unsigned short* __restrict__ vt,
    int M, int N, int K)
{
    __shared__ unsigned short a_lds[128 * 64];
    __shared__ unsigned short b_lds[128 * 64];
    int t = threadIdx.x;
    int w = t >> 6, lane = t & 63, quad = lane >> 4, l15 = lane & 15;
    int mb = blockIdx.y * 128, nb = blockIdx.x * 128;
    int wm = (w >> 1) * 64, wn = (w & 1) * 64;

    // staging addresses: lane ℓ covers row ℓ/8, physical chunk ℓ%8 of its
    // wave's 8-row stripe; global chunk = (ℓ%8) ^ (ℓ/8)  (XOR swizzle)
    int lr = lane >> 3;
    int lcol = ((lane & 7) ^ lr) * 8;
    const unsigned short* pa = A + (size_t)(mb + w * 32 + lr) * K + lcol;
    const unsigned short* pb = B + (size_t)(nb + w * 32 + lr) * K + lcol;
    unsigned short* la = &a_lds[(w * 32) * 64];
    unsigned short* lb = &b_lds[(w * 32) * 64];

    floatx4 acc[4][4];
    for (int i = 0; i < 4; i++)
        for (int j = 0; j < 4; j++) acc[i][j] = (floatx4)0.0f;

    for (int k0 = 0; k0 < K; k0 += 64) {
        for (int it = 0; it < 4; it++) {
            gl_lds16(pa + k0 + (size_t)it * 8 * K, la + it * 8 * 64);
            gl_lds16(pb + k0 + (size_t)it * 8 * K, lb + it * 8 * 64);
        }
        __syncthreads();
        for (int ks = 0; ks < 2; ks++) {
            short8 af[4], bfr[4];
            for (int i = 0; i < 4; i++) {
                int r = wm + i * 16 + l15;
                af[i] = *(const short8*)&a_lds[r * 64 + (((ks * 4 + quad) ^ (l15 & 7)) * 8)];
            }
            for (int j = 0; j < 4; j++) {
                int r = wn + j * 16 + l15;
                bfr[j] = *(const short8*)&b_lds[r * 64 + (((ks * 4 + quad) ^ (l15 & 7)) * 8)];
            }
            for (int i = 0; i < 4; i++)
                for (int j = 0; j < 4; j++)
                    acc[i][j] = __builtin_amdgcn_mfma_f32_16x16x32_bf16(af[i], bfr[j], acc[i][j], 0, 0, 0);
        }
        __syncthreads();
    }

    if (MODE == 1) {
        int type = blockIdx.x % 3;   // 0=Q 1=K 2=V (384 = 3*128)
        int h = blockIdx.x / 3;
        if (type == 2) {
            // V block -> vt[h][d][s], lane packs its 4 consecutive rows (8B store)
            for (int j = 0; j < 4; j++) {
                int local = wn + j * 16 + l15;
                float bv = bias[nb + local];
                unsigned short* vp = vt + ((size_t)h * HDIM + local) * S_LEN;
                for (int i = 0; i < 4; i++) {
                    int rowbase = mb + wm + i * 16 + quad * 4;
                    ushort4v pk;
                    for (int r = 0; r < 4; r++) pk[r] = f2bf(acc[i][j][r] + bv);
                    *(ushort4v*)&vp[rowbase] = pk;
                }
            }
        } else {
            size_t colbase = (size_t)h * 256 + type * 128;
            for (int j = 0; j < 4; j++) {
                int local = wn + j * 16 + l15;
                float bv = bias[nb + local];
                for (int i = 0; i < 4; i++) {
                    int rowbase = mb + wm + i * 16 + quad * 4;
                    for (int r = 0; r < 4; r++)
                        Cq[(size_t)(rowbase + r) * QK_STRIDE + colbase + local] =
                            f2bf(acc[i][j][r] + bv);
                }
            }
        }
    } else {
        for (int j = 0; j < 4; j++) {
            int col = nb + wn + j * 16 + l15;
            float bv = bias[col];
            for (int i = 0; i < 4; i++) {
                int rowbase = mb + wm + i * 16 + quad * 4;
                for (int r = 0; r < 4; r++)
                    Cf[(size_t)(rowbase + r) * N + col] = acc[i][j][r] + bv;
            }
        }
    }
}

// ---------------------------------------------------------------------------
// Flash attention, causal + alibi. One block per (head, 64-row q tile).
// Q/K from compact [S][8192] (head h: Q at h*256, K at h*256+128),
// V pre-transposed in vt[h][d][s] -> pure vector staging, no per-tile
// transpose.
// ---------------------------------------------------------------------------
__global__ __launch_bounds__(256) void attn_flash(
    const unsigned short* __restrict__ qk,      // [S][8192] bf16
    const unsigned short* __restrict__ vt,      // [NH][128][S] bf16
    const float* __restrict__ alibi,            // [NH][S] fp32
    unsigned short* __restrict__ ctx)           // [S][4096] bf16
{
    __shared__ unsigned short k_lds[64 * 136];   // [key][d], pad 128->136
    __shared__ unsigned short vt_lds[128 * 72];  // [d][key], pad 64->72
    __shared__ unsigned short p_lds[4 * 16 * 72];

    int h = blockIdx.x;
    int qb = blockIdx.y * 64;
    int t = threadIdx.x;
    int w = t >> 6, lane = t & 63, quad = lane >> 4, l15 = lane & 15;
    int qoff = h * 256;

    // Q fragments (A-layout) for this wave's 16 q rows, all 128 dims
    short8 qf[4];
    {
        int qrow = qb + w * 16 + l15;
        const unsigned short* qp = qk + (size_t)qrow * QK_STRIDE + qoff;
        for (int ks = 0; ks < 4; ks++)
            qf[ks] = *(const short8*)&qp[ks * 32 + quad * 8];
    }

    floatx4 o[8];
    for (int j = 0; j < 8; j++) o[j] = (floatx4)0.0f;
    float m_prev[4], l_prev[4];
    for (int r = 0; r < 4; r++) { m_prev[r] = -INFINITY; l_prev[r] = 0.0f; }

    int ntiles = qb / 64 + 1;
    for (int tile = 0; tile < ntiles; tile++) {
        int kb = tile * 64;
        // stage K tile [64][128] from qk, V^T tile [128][64] from vt
        for (int i = 0; i < 4; i++) {
            int idx = t + 256 * i;
            int krow = idx >> 4, kcol = (idx & 15) * 8;
            *(short8*)&k_lds[krow * 136 + kcol] =
                *(const short8*)(qk + (size_t)(kb + krow) * QK_STRIDE + qoff + 128 + kcol);
            int d = idx >> 3, ch = (idx & 7) * 8;
            *(short8*)&vt_lds[d * 72 + ch] =
                *(const short8*)(vt + ((size_t)h * HDIM + d) * S_LEN + kb + ch);
        }
        __syncthreads();

        // S = Q K^T (per wave: 16 q-rows x 64 keys)
        floatx4 s[4];
        for (int j = 0; j < 4; j++) s[j] = (floatx4)0.0f;
        for (int ks = 0; ks < 4; ks++) {
            for (int j = 0; j < 4; j++) {
                short8 bfr = *(const short8*)&k_lds[(j * 16 + l15) * 136 + ks * 32 + quad * 8];
                s[j] = __builtin_amdgcn_mfma_f32_16x16x32_bf16(qf[ks], bfr, s[j], 0, 0, 0);
            }
        }

        // scale + alibi + causal mask
        float sv[4][4];
        for (int j = 0; j < 4; j++) {
            int kcol = kb + j * 16 + l15;
            float al = alibi[h * S_LEN + kcol];
            for (int r = 0; r < 4; r++) {
                int qrow = qb + w * 16 + quad * 4 + r;
                float x = s[j][r] * INV_NORM + al;
                sv[j][r] = (kcol <= qrow) ? x : -INFINITY;
            }
        }

        // online softmax per q-row (rows live in one 16-lane group)
        float p[4][4];
        for (int r = 0; r < 4; r++) {
            float mt = fmaxf(fmaxf(sv[0][r], sv[1][r]), fmaxf(sv[2][r], sv[3][r]));
            for (int off = 1; off < 16; off <<= 1)
                mt = fmaxf(mt, __shfl_xor(mt, off, 64));
            float m_new = fmaxf(m_prev[r], mt);
            float alpha = __expf(m_prev[r] - m_new);   // exp(-inf)=0 first tile
            float rs = 0.0f;
            for (int j = 0; j < 4; j++) {
                float pv = __expf(sv[j][r] - m_new);   // masked -> exp(-inf)=0
                p[j][r] = pv;
                rs += pv;
            }
            for (int off = 1; off < 16; off <<= 1)
                rs += __shfl_xor(rs, off, 64);
            l_prev[r] = l_prev[r] * alpha + rs;
            m_prev[r] = m_new;
            for (int j = 0; j < 8; j++) o[j][r] *= alpha;
        }

        // P (C-layout) -> LDS -> A-layout fragments (per-wave region)
        {
            unsigned short* pb = &p_lds[w * 16 * 72];
            for (int j = 0; j < 4; j++)
                for (int r = 0; r < 4; r++)
                    pb[(quad * 4 + r) * 72 + j * 16 + l15] = f2bf(p[j][r]);
        }
        {
            const unsigned short* pb = &p_lds[w * 16 * 72];
            for (int ks = 0; ks < 2; ks++) {
                short8 ap = *(const short8*)&pb[l15 * 72 + ks * 32 + quad * 8];
                for (int j = 0; j < 8; j++) {
                    short8 bv = *(const short8*)&vt_lds[(j * 16 + l15) * 72 + ks * 32 + quad * 8];
                    o[j] = __builtin_amdgcn_mfma_f32_16x16x32_bf16(ap, bv, o[j], 0, 0, 0);
                }
            }
        }
        __syncthreads();
    }

    // normalize and store ctx in [S][HID] layout (head h at cols h*128..)
    for (int r = 0; r < 4; r++) {
        float linv = 1.0f / l_prev[r];
        int qrow = qb + w * 16 + quad * 4 + r;
        unsigned short* op = ctx + (size_t)qrow * HID_DIM + h * HDIM;
        for (int j = 0; j < 8; j++)
            op[j * 16 + l15] = f2bf(o[j][r] * linv);
    }
}

extern "C" void kernel_launch(void* const* d_in, const int* in_sizes, int n_in,
                              void* d_out, int out_size, void* d_ws, size_t ws_size,
                              hipStream_t stream) {
    const float* hidden  = (const float*)d_in[0];  // [1,2048,4096] fp32
    const float* alibi   = (const float*)d_in[1];  // [32,1,2048]   fp32
    const float* w_qkv   = (const float*)d_in[2];  // [12288,4096]  fp32
    const float* b_qkv   = (const float*)d_in[3];  // [12288]       fp32
    const float* w_dense = (const float*)d_in[4];  // [4096,4096]   fp32
    const float* b_dense = (const float*)d_in[5];  // [4096]        fp32
    float* out = (float*)d_out;                    // [2048,4096]   fp32

    // ws layout (ushort elements), with overlays (stream order makes it safe):
    //   [0 .. 50.3M)   wq_bf  (w_qkv bf16)      -- reused for wd_bf after QKV
    //   [+16.8M)       fused  [S][8192] Q/K compact
    //   [+8.4M)        vt     [NH][128][S]
    //   [+8.4M)        hbf    (hidden bf16)     -- reused as ctx after QKV
    unsigned short* ws    = (unsigned short*)d_ws;
    unsigned short* wq_bf = ws;
    unsigned short* fused = ws + (size_t)50331648;
    unsigned short* vt    = fused + (size_t)S_LEN * QK_STRIDE;      // +16,777,216
    unsigned short* hbf   = vt + (size_t)NHEADS * HDIM * S_LEN;     // +8,388,608
    unsigned short* ctx   = hbf;   // overlay: hbf dead after QKV GEMM
    unsigned short* wd_bf = wq_bf; // overlay: wq_bf dead after QKV GEMM

    dim3 blk(256);
    // converts (8 elems/thread, exact grids)
    cvt_bf16<<<dim3(4096),  blk, 0, stream>>>(hidden,  hbf);     // 8,388,608
    cvt_bf16<<<dim3(24576), blk, 0, stream>>>(w_qkv,   wq_bf);   // 50,331,648
    // QKV projection -> fused Q/K + transposed V
    gemm_bt<1><<<dim3(QKV_N / 128, S_LEN / 128), blk, 0, stream>>>(
        hbf, wq_bf, b_qkv, fused, nullptr, vt, S_LEN, QKV_N, HID_DIM);
    // attention
    attn_flash<<<dim3(NHEADS, S_LEN / 64), blk, 0, stream>>>(fused, vt, alibi, ctx);
    // dense weight convert (overlays wq_bf, safe after QKV GEMM)
    cvt_bf16<<<dim3(8192), blk, 0, stream>>>(w_dense, wd_bf);    // 16,777,216
    // output projection (fp32 out)
    gemm_bt<0><<<dim3(HID_DIM / 128, S_LEN / 128), blk, 0, stream>>>(
        ctx, wd_bf, b_dense, nullptr, out, nullptr, S_LEN, HID_DIM, HID_DIM);
}